// Round 2
// baseline (1213.563 us; speedup 1.0000x reference)
//
#include <hip/hip_runtime.h>
#include <stdint.h>

#define B_ 32
#define S_ 8192
#define D_ 256
#define Q_ 256
#define U_ 128
#define NCHUNK 128   // S_/64 chunks per batch (M=64 rows per block)

typedef float floatx4 __attribute__((ext_vector_type(4)));
typedef float f32x4 __attribute__((ext_vector_type(4)));
typedef __bf16 bf16x8 __attribute__((ext_vector_type(8)));
typedef unsigned short ushortx4 __attribute__((ext_vector_type(4)));
typedef unsigned short ushortx8 __attribute__((ext_vector_type(8)));

static __device__ __forceinline__ unsigned short f2bf(float f) {
    unsigned int x = __builtin_bit_cast(unsigned int, f);
    x += 0x7FFFu + ((x >> 16) & 1u);   // RNE (inputs are finite/normal)
    return (unsigned short)(x >> 16);
}

static __device__ __forceinline__ float bf2f(unsigned short u) {
    unsigned int x = ((unsigned int)u) << 16;
    return __builtin_bit_cast(float, x);
}

static __device__ __forceinline__ float fast_tanh(float x) {
    x = fminf(15.f, fmaxf(-15.f, x));
    float e = __expf(2.f * x);
    return __fdividef(e - 1.f, e + 1.f);
}

// Kernel 1: proj_q[b][u] = sum_q query[b][q]*W2[q][u]; W1^T -> bf16 in ws,
// fragment-major layout: element (n,k) at (k>>5)*4096 + n*32 + (k&31).
// Also zeroes the per-b completion counters (ws is harness-poisoned).
__global__ __launch_bounds__(128) void prep_kernel(
        const float* __restrict__ query, const float* __restrict__ W1,
        const float* __restrict__ W2, float* __restrict__ pq,
        unsigned short* __restrict__ w1t, unsigned int* __restrict__ cnt) {
    int b = blockIdx.x;
    int t = threadIdx.x;  // 0..127
    if (t == 0) cnt[b] = 0u;
    __shared__ float qrow[Q_];
    qrow[t] = query[b * Q_ + t];
    qrow[t + 128] = query[b * Q_ + 128 + t];
    __syncthreads();
    float acc = 0.f;
#pragma unroll 8
    for (int q = 0; q < Q_; ++q) acc = fmaf(qrow[q], W2[q * U_ + t], acc);
    pq[b * U_ + t] = acc;
    int base = (b * 128 + t) * 8;     // 8 consecutive elements, same n
    int n = base >> 8, k0 = base & 255;
    ushortx8 u;
#pragma unroll
    for (int j = 0; j < 8; ++j) u[j] = f2bf(W1[(k0 + j) * U_ + n]);
    *reinterpret_cast<ushortx8*>(&w1t[(k0 >> 5) * 4096 + n * 32 + (k0 & 31)]) = u;
}

// Kernel 2 (fused): per (b, 64-row chunk):
//   A tile 64x256 bf16 in LDS (32 KiB, XOR swizzle). Staging is FULLY
//   SEQUENTIAL over the block's 64 KiB of values (8 passes x 8 rows;
//   each wave writes a contiguous 1 KiB swizzled LDS span -> conflict-free),
//   single barrier, then the 8-ksg MFMA sweep (B fragments direct from
//   L2-hot w1t, register double-buffer). HBM-bound: inter-block TLP
//   (4 blocks/CU) covers the stage->MFMA serialization.
//   Tail: last block per b (agent-scope atomic) does the softmax combine
//   and writes final weights + context -> no third kernel.
__global__ __launch_bounds__(256, 4) void fused_kernel(
        const float* __restrict__ values, const unsigned short* __restrict__ w1t,
        const float* __restrict__ pq, const float* __restrict__ V,
        float* __restrict__ scores, float* __restrict__ mbuf,
        float* __restrict__ lbuf, float* __restrict__ cpart,
        unsigned int* __restrict__ cnt, float* __restrict__ out) {
    __shared__ __align__(16) char smem[32768 + 4096 + 512 + 256];
    unsigned short* As = (unsigned short*)smem;            // 64 x 256 ushorts, swizzled
    floatx4* cbuf = (floatx4*)(smem + 32768);              // 256 f4
    float* part = (float*)(smem + 32768 + 4096);           // 128 f (tail: alpha)
    float* parr = (float*)(smem + 32768 + 4096 + 512);     // 64 f  (tail: wred)
    __shared__ int lastdone;

    int b = blockIdx.y;
    int cid = blockIdx.x;
    int s0 = cid * 64;
    int tid = threadIdx.x;
    int lane = tid & 63;
    int wave = tid >> 6;
    int wr = wave >> 1, wc = wave & 1;
    int cc = lane & 15, qg = lane >> 4;
    int cc7 = cc & 7;

    const float* vb = values + ((size_t)b * S_ + s0) * D_;

    f32x4 acc[2][4];
#pragma unroll
    for (int mt = 0; mt < 2; ++mt)
#pragma unroll
        for (int nt = 0; nt < 4; ++nt) acc[mt][nt] = (f32x4){0.f, 0.f, 0.f, 0.f};

    // B fragment register double-buffer, direct from global (L2/L1-hot).
    bf16x8 bb[2][4];
    const unsigned short* wbase = w1t + (wc * 64 + cc) * 32 + qg * 8;
    auto load_b = [&](int ksg, int buf) {
#pragma unroll
        for (int nt = 0; nt < 4; ++nt)
            bb[buf][nt] = *reinterpret_cast<const bf16x8*>(wbase + ksg * 4096 + nt * 512);
    };
    load_b(0, 0);   // in flight across the whole staging phase

    // A staging: sequential 64 KiB burst. Pass p covers rows [p*8, p*8+8):
    // thread t handles row p*8 + (t>>5), 32-B chunk (t&31) -> one
    // ds_write_b128; a wave writes 2 full rows = contiguous 1 KiB of LDS
    // (XOR swizzle is a within-row permutation) -> conflict-free.
    int srow = tid >> 5;        // 0..7
    int sc = tid & 31;          // 16-B chunk index within row
    floatx4 areg[2][2];
    auto load_p = [&](int p) {
        const float* src = vb + (size_t)(p * 8 + srow) * D_ + sc * 8;
        areg[p & 1][0] = *reinterpret_cast<const floatx4*>(src);
        areg[p & 1][1] = *reinterpret_cast<const floatx4*>(src + 4);
    };
    auto write_p = [&](int p) {
        int row = p * 8 + srow;
        ushortx8 u;
#pragma unroll
        for (int e = 0; e < 4; ++e) {
            u[e]     = f2bf(areg[p & 1][0][e]);
            u[e + 4] = f2bf(areg[p & 1][1][e]);
        }
        *reinterpret_cast<ushortx8*>(&As[row * 256 + ((sc ^ (row & 7)) << 3)]) = u;
    };

    load_p(0); load_p(1);
#pragma unroll
    for (int p = 0; p < 8; ++p) {
        write_p(p);
        if (p < 6) load_p(p + 2);
    }
    __syncthreads();

    // MFMA sweep: 8 ksg, no intermediate barriers.
#pragma unroll
    for (int ksg = 0; ksg < 8; ++ksg) {
        if (ksg < 7) load_b(ksg + 1, (ksg + 1) & 1);
        bf16x8 af[2];
#pragma unroll
        for (int mt = 0; mt < 2; ++mt) {
            int r = wr * 32 + mt * 16 + cc;
            af[mt] = *reinterpret_cast<const bf16x8*>(
                &As[r * 256 + (((ksg * 4 + qg) ^ cc7) << 3)]);
        }
        __builtin_amdgcn_s_setprio(1);
#pragma unroll
        for (int mt = 0; mt < 2; ++mt)
#pragma unroll
            for (int nt = 0; nt < 4; ++nt)
                acc[mt][nt] = __builtin_amdgcn_mfma_f32_16x16x32_bf16(
                    af[mt], bb[ksg & 1][nt], acc[mt][nt], 0, 0, 0);
        __builtin_amdgcn_s_setprio(0);
    }

    // tanh + dot-V epilogue -> per-row score partials
    float Vu[4], pqu[4];
#pragma unroll
    for (int nt = 0; nt < 4; ++nt) {
        int u = wc * 64 + nt * 16 + cc;
        Vu[nt] = V[u];
        pqu[nt] = pq[b * U_ + u];
    }
#pragma unroll
    for (int mt = 0; mt < 2; ++mt) {
#pragma unroll
        for (int r = 0; r < 4; ++r) {
            float s = 0.f;
#pragma unroll
            for (int nt = 0; nt < 4; ++nt)
                s += Vu[nt] * fast_tanh(acc[mt][nt][r] + pqu[nt]);
            s += __shfl_xor(s, 1);
            s += __shfl_xor(s, 2);
            s += __shfl_xor(s, 4);
            s += __shfl_xor(s, 8);
            if (cc == 0) part[wc * 64 + wr * 32 + mt * 16 + qg * 4 + r] = s;
        }
    }
    __syncthreads();
    // combine halves, write scores, butterfly max+sum (result in every lane)
    if (tid < 64) {
        float sc2 = part[tid] + part[64 + tid];
        scores[(size_t)b * S_ + s0 + tid] = sc2;
        float m = sc2;
#pragma unroll
        for (int off = 32; off >= 1; off >>= 1) m = fmaxf(m, __shfl_xor(m, off));
        float p = __expf(sc2 - m);
        float l = p;
#pragma unroll
        for (int off = 32; off >= 1; off >>= 1) l += __shfl_xor(l, off);
        parr[tid] = p;
        if (tid == 0) { mbuf[b * NCHUNK + cid] = m; lbuf[b * NCHUNK + cid] = l; }
    }
    __syncthreads();

    // partial context from LDS bf16 tile (wave-uniform row; conflict-free).
    int g = tid & 63, sub = tid >> 6;
    floatx4 acc4 = {0.f, 0.f, 0.f, 0.f};
#pragma unroll 4
    for (int i = 0; i < 16; ++i) {
        int r = i * 4 + sub;
        float w = parr[r];
        int addr = r * 256 + (((g >> 1) ^ (r & 7)) << 3) + (g & 1) * 4;
        ushortx4 u = *reinterpret_cast<const ushortx4*>(&As[addr]);
        acc4[0] = fmaf(bf2f(u[0]), w, acc4[0]);
        acc4[1] = fmaf(bf2f(u[1]), w, acc4[1]);
        acc4[2] = fmaf(bf2f(u[2]), w, acc4[2]);
        acc4[3] = fmaf(bf2f(u[3]), w, acc4[3]);
    }
    cbuf[tid] = acc4;
    __syncthreads();
    if (tid < 64) {
        floatx4 r4 = cbuf[tid] + cbuf[tid + 64] + cbuf[tid + 128] + cbuf[tid + 192];
        *reinterpret_cast<floatx4*>(cpart + ((size_t)b * NCHUNK + cid) * D_ + g * 4) = r4;
    }

    // ---- last-block-per-b finalize (replaces kernel 3) ----
    __threadfence();            // release this block's global writes
    __syncthreads();
    if (tid == 0) {
        unsigned int old = __hip_atomic_fetch_add(&cnt[b], 1u,
                                                  __ATOMIC_ACQ_REL,
                                                  __HIP_MEMORY_SCOPE_AGENT);
        lastdone = (old == NCHUNK - 1);
    }
    __syncthreads();
    if (!lastdone) return;
    __threadfence();            // acquire all other blocks' writes

    float* alphaF = part;       // 128 f (As/cbuf region dead)
    float* wredF  = parr;       // 4 f
    if (tid < NCHUNK) {
        float m = mbuf[b * NCHUNK + tid];
#pragma unroll
        for (int off = 32; off >= 1; off >>= 1) m = fmaxf(m, __shfl_xor(m, off));
        if ((tid & 63) == 0) wredF[tid >> 6] = m;
    }
    __syncthreads();
    float M = fmaxf(wredF[0], wredF[1]);
    if (tid < NCHUNK) {
        float z = lbuf[b * NCHUNK + tid] * __expf(mbuf[b * NCHUNK + tid] - M);
#pragma unroll
        for (int off = 32; off >= 1; off >>= 1) z += __shfl_xor(z, off);
        if ((tid & 63) == 0) wredF[2 + (tid >> 6)] = z;
    }
    __syncthreads();
    float invZ = 1.f / (wredF[2] + wredF[3]);
    if (tid < NCHUNK) alphaF[tid] = __expf(mbuf[b * NCHUNK + tid] - M) * invZ;

    // final attention weights for this b (1024 float4s, 4 per thread... 8)
    const floatx4* sv = (const floatx4*)(scores + (size_t)b * S_);
    floatx4* wv = (floatx4*)(out + B_ * D_ + (size_t)b * S_);
#pragma unroll
    for (int i = 0; i < 8; ++i) {
        floatx4 v = sv[i * 256 + tid];
        floatx4 w;
#pragma unroll
        for (int j = 0; j < 4; ++j) w[j] = __expf(v[j] - M) * invZ;
        wv[i * 256 + tid] = w;
    }
    __syncthreads();            // alphaF ready for all threads
    float ctx = 0.f;
#pragma unroll 8
    for (int c = 0; c < NCHUNK; ++c)
        ctx = fmaf(alphaF[c], cpart[((size_t)b * NCHUNK + c) * D_ + tid], ctx);
    out[b * D_ + tid] = ctx;
}

extern "C" void kernel_launch(void* const* d_in, const int* in_sizes, int n_in,
                              void* d_out, int out_size, void* d_ws, size_t ws_size,
                              hipStream_t stream) {
    const float* query  = (const float*)d_in[0];
    const float* values = (const float*)d_in[1];
    const float* W1     = (const float*)d_in[2];
    const float* W2     = (const float*)d_in[3];
    const float* V      = (const float*)d_in[4];
    float* out = (float*)d_out;

    char* ws = (char*)d_ws;
    unsigned short* w1t = (unsigned short*)ws;               ws += 65536;           // 64 KiB
    float* pq     = (float*)ws;                              ws += 16384;           // 16 KiB
    float* scores = (float*)ws;                              ws += B_ * S_ * 4;     // 1 MiB
    float* mbuf   = (float*)ws;                              ws += B_ * NCHUNK * 4; // 16 KiB
    float* lbuf   = (float*)ws;                              ws += B_ * NCHUNK * 4; // 16 KiB
    unsigned int* cnt = (unsigned int*)ws;                   ws += 128;             // 32 ctrs
    float* cpart  = (float*)ws;                                                    // 4 MiB

    prep_kernel<<<dim3(32), dim3(128), 0, stream>>>(query, W1, W2, pq, w1t, cnt);
    fused_kernel<<<dim3(NCHUNK, B_), dim3(256), 0, stream>>>(values, w1t, pq, V,
                                                             scores, mbuf, lbuf,
                                                             cpart, cnt, out);
}

// Round 3
// 387.293 us; speedup vs baseline: 3.1334x; 3.1334x over previous
//
#include <hip/hip_runtime.h>
#include <stdint.h>

#define B_ 32
#define S_ 8192
#define D_ 256
#define Q_ 256
#define U_ 128
#define NCHUNK 128   // S_/64 chunks per batch (M=64 rows per block)

typedef float floatx4 __attribute__((ext_vector_type(4)));
typedef float f32x4 __attribute__((ext_vector_type(4)));
typedef __bf16 bf16x8 __attribute__((ext_vector_type(8)));
typedef unsigned short ushortx4 __attribute__((ext_vector_type(4)));
typedef unsigned short ushortx8 __attribute__((ext_vector_type(8)));

static __device__ __forceinline__ unsigned short f2bf(float f) {
    unsigned int x = __builtin_bit_cast(unsigned int, f);
    x += 0x7FFFu + ((x >> 16) & 1u);   // RNE (inputs are finite/normal)
    return (unsigned short)(x >> 16);
}

static __device__ __forceinline__ float bf2f(unsigned short u) {
    unsigned int x = ((unsigned int)u) << 16;
    return __builtin_bit_cast(float, x);
}

static __device__ __forceinline__ float fast_tanh(float x) {
    x = fminf(15.f, fmaxf(-15.f, x));
    float e = __expf(2.f * x);
    return __fdividef(e - 1.f, e + 1.f);
}

// Kernel 1: proj_q[b][u] = sum_q query[b][q]*W2[q][u]; W1^T -> bf16 in ws,
// fragment-major layout: element (n,k) at (k>>5)*4096 + n*32 + (k&31).
// A wave's MFMA B-fragment load is then one contiguous, coalesced 1 KiB
// region -> direct global->reg in the fused kernel, no LDS for B.
__global__ __launch_bounds__(128) void prep_kernel(
        const float* __restrict__ query, const float* __restrict__ W1,
        const float* __restrict__ W2, float* __restrict__ pq,
        unsigned short* __restrict__ w1t) {
    int b = blockIdx.x;
    int t = threadIdx.x;  // 0..127
    __shared__ float qrow[Q_];
    qrow[t] = query[b * Q_ + t];
    qrow[t + 128] = query[b * Q_ + 128 + t];
    __syncthreads();
    float a0 = 0.f, a1 = 0.f, a2 = 0.f, a3 = 0.f;   // 4-way ILP on the chain
#pragma unroll 4
    for (int q = 0; q < Q_; q += 4) {
        a0 = fmaf(qrow[q],     W2[q * U_ + t],           a0);
        a1 = fmaf(qrow[q + 1], W2[(q + 1) * U_ + t],     a1);
        a2 = fmaf(qrow[q + 2], W2[(q + 2) * U_ + t],     a2);
        a3 = fmaf(qrow[q + 3], W2[(q + 3) * U_ + t],     a3);
    }
    pq[b * U_ + t] = (a0 + a1) + (a2 + a3);
    int base = (b * 128 + t) * 8;     // 8 consecutive elements, same n
    int n = base >> 8, k0 = base & 255;
    ushortx8 u;
#pragma unroll
    for (int j = 0; j < 8; ++j) u[j] = f2bf(W1[(k0 + j) * U_ + n]);
    *reinterpret_cast<ushortx8*>(&w1t[(k0 >> 5) * 4096 + n * 32 + (k0 & 31)]) = u;
}

// Kernel 2 (fused): per (b, 64-row chunk):
//   A tile 64x256 bf16 in LDS (32 KiB, XOR swizzle). Staging is FULLY
//   SEQUENTIAL over the block's 64 KiB of values (8 passes x 8 rows;
//   each wave writes a contiguous 1 KiB swizzled LDS span -> conflict-free),
//   single barrier, then the 8-ksg MFMA sweep (B fragments direct from
//   L2-hot w1t, register double-buffer). HBM-bound: inter-block TLP
//   (4 blocks/CU) covers the stage->MFMA serialization. Scores -> ws;
//   local softmax stats; partial context from LDS bf16 (single HBM pass
//   over values). NO device-scope fences (round-2 lesson: per-block
//   __threadfence => buffer_wbl2/inv per block => 15x regression).
__global__ __launch_bounds__(256, 4) void fused_kernel(
        const float* __restrict__ values, const unsigned short* __restrict__ w1t,
        const float* __restrict__ pq, const float* __restrict__ V,
        float* __restrict__ scores, float* __restrict__ mbuf,
        float* __restrict__ lbuf, float* __restrict__ cpart) {
    __shared__ __align__(16) char smem[32768 + 4096 + 512 + 256];
    unsigned short* As = (unsigned short*)smem;            // 64 x 256 ushorts, swizzled
    floatx4* cbuf = (floatx4*)(smem + 32768);              // 256 f4
    float* part = (float*)(smem + 32768 + 4096);           // 128 f
    float* parr = (float*)(smem + 32768 + 4096 + 512);     // 64 f

    int b = blockIdx.y;
    int cid = blockIdx.x;
    int s0 = cid * 64;
    int tid = threadIdx.x;
    int lane = tid & 63;
    int wave = tid >> 6;
    int wr = wave >> 1, wc = wave & 1;
    int cc = lane & 15, qg = lane >> 4;
    int cc7 = cc & 7;

    const float* vb = values + ((size_t)b * S_ + s0) * D_;

    f32x4 acc[2][4];
#pragma unroll
    for (int mt = 0; mt < 2; ++mt)
#pragma unroll
        for (int nt = 0; nt < 4; ++nt) acc[mt][nt] = (f32x4){0.f, 0.f, 0.f, 0.f};

    // B fragment register double-buffer, direct from global (L2/L1-hot).
    bf16x8 bb[2][4];
    const unsigned short* wbase = w1t + (wc * 64 + cc) * 32 + qg * 8;
    auto load_b = [&](int ksg, int buf) {
#pragma unroll
        for (int nt = 0; nt < 4; ++nt)
            bb[buf][nt] = *reinterpret_cast<const bf16x8*>(wbase + ksg * 4096 + nt * 512);
    };
    load_b(0, 0);   // in flight across the whole staging phase

    // A staging: sequential 64 KiB burst. Pass p covers rows [p*8, p*8+8):
    // thread t handles row p*8 + (t>>5), 16-B chunk (t&31) -> one
    // ds_write_b128; a wave writes 2 full rows = contiguous 1 KiB of LDS
    // (XOR swizzle is a within-row permutation) -> conflict-free.
    int srow = tid >> 5;        // 0..7
    int sc = tid & 31;          // 16-B chunk index within row
    floatx4 areg[2][2];
    auto load_p = [&](int p) {
        const float* src = vb + (size_t)(p * 8 + srow) * D_ + sc * 8;
        areg[p & 1][0] = *reinterpret_cast<const floatx4*>(src);
        areg[p & 1][1] = *reinterpret_cast<const floatx4*>(src + 4);
    };
    auto write_p = [&](int p) {
        int row = p * 8 + srow;
        ushortx8 u;
#pragma unroll
        for (int e = 0; e < 4; ++e) {
            u[e]     = f2bf(areg[p & 1][0][e]);
            u[e + 4] = f2bf(areg[p & 1][1][e]);
        }
        *reinterpret_cast<ushortx8*>(&As[row * 256 + ((sc ^ (row & 7)) << 3)]) = u;
    };

    load_p(0); load_p(1);
#pragma unroll
    for (int p = 0; p < 8; ++p) {
        write_p(p);
        if (p < 6) load_p(p + 2);
    }
    __syncthreads();

    // MFMA sweep: 8 ksg, no intermediate barriers.
#pragma unroll
    for (int ksg = 0; ksg < 8; ++ksg) {
        if (ksg < 7) load_b(ksg + 1, (ksg + 1) & 1);
        bf16x8 af[2];
#pragma unroll
        for (int mt = 0; mt < 2; ++mt) {
            int r = wr * 32 + mt * 16 + cc;
            af[mt] = *reinterpret_cast<const bf16x8*>(
                &As[r * 256 + (((ksg * 4 + qg) ^ cc7) << 3)]);
        }
        __builtin_amdgcn_s_setprio(1);
#pragma unroll
        for (int mt = 0; mt < 2; ++mt)
#pragma unroll
            for (int nt = 0; nt < 4; ++nt)
                acc[mt][nt] = __builtin_amdgcn_mfma_f32_16x16x32_bf16(
                    af[mt], bb[ksg & 1][nt], acc[mt][nt], 0, 0, 0);
        __builtin_amdgcn_s_setprio(0);
    }

    // tanh + dot-V epilogue -> per-row score partials
    float Vu[4], pqu[4];
#pragma unroll
    for (int nt = 0; nt < 4; ++nt) {
        int u = wc * 64 + nt * 16 + cc;
        Vu[nt] = V[u];
        pqu[nt] = pq[b * U_ + u];
    }
#pragma unroll
    for (int mt = 0; mt < 2; ++mt) {
#pragma unroll
        for (int r = 0; r < 4; ++r) {
            float s = 0.f;
#pragma unroll
            for (int nt = 0; nt < 4; ++nt)
                s += Vu[nt] * fast_tanh(acc[mt][nt][r] + pqu[nt]);
            s += __shfl_xor(s, 1);
            s += __shfl_xor(s, 2);
            s += __shfl_xor(s, 4);
            s += __shfl_xor(s, 8);
            if (cc == 0) part[wc * 64 + wr * 32 + mt * 16 + qg * 4 + r] = s;
        }
    }
    __syncthreads();
    // combine halves, write scores, butterfly max+sum (result in every lane)
    if (tid < 64) {
        float sc2 = part[tid] + part[64 + tid];
        scores[(size_t)b * S_ + s0 + tid] = sc2;
        float m = sc2;
#pragma unroll
        for (int off = 32; off >= 1; off >>= 1) m = fmaxf(m, __shfl_xor(m, off));
        float p = __expf(sc2 - m);
        float l = p;
#pragma unroll
        for (int off = 32; off >= 1; off >>= 1) l += __shfl_xor(l, off);
        parr[tid] = p;
        if (tid == 0) { mbuf[b * NCHUNK + cid] = m; lbuf[b * NCHUNK + cid] = l; }
    }
    __syncthreads();

    // partial context from LDS bf16 tile (wave-uniform row; conflict-free).
    int g = tid & 63, sub = tid >> 6;
    floatx4 acc4 = {0.f, 0.f, 0.f, 0.f};
#pragma unroll 4
    for (int i = 0; i < 16; ++i) {
        int r = i * 4 + sub;
        float w = parr[r];
        int addr = r * 256 + (((g >> 1) ^ (r & 7)) << 3) + (g & 1) * 4;
        ushortx4 u = *reinterpret_cast<const ushortx4*>(&As[addr]);
        acc4[0] = fmaf(bf2f(u[0]), w, acc4[0]);
        acc4[1] = fmaf(bf2f(u[1]), w, acc4[1]);
        acc4[2] = fmaf(bf2f(u[2]), w, acc4[2]);
        acc4[3] = fmaf(bf2f(u[3]), w, acc4[3]);
    }
    cbuf[tid] = acc4;
    __syncthreads();
    if (tid < 64) {
        floatx4 r4 = cbuf[tid] + cbuf[tid + 64] + cbuf[tid + 128] + cbuf[tid + 192];
        *reinterpret_cast<floatx4*>(cpart + ((size_t)b * NCHUNK + cid) * D_ + g * 4) = r4;
    }
}

// Kernel 3: grid (B_, 9). y<8: write 1024 weights; y==8: combined context.
__global__ __launch_bounds__(256) void finalize_kernel(
        const float* __restrict__ scores, const float* __restrict__ mbuf,
        const float* __restrict__ lbuf, const float* __restrict__ cpart,
        float* __restrict__ out) {
    int b = blockIdx.x;
    int part_id = blockIdx.y;
    int tid = threadIdx.x;
    __shared__ float wred[4];
    __shared__ float alpha[NCHUNK];
    if (tid < NCHUNK) {
        float m = mbuf[b * NCHUNK + tid];
#pragma unroll
        for (int off = 32; off >= 1; off >>= 1) m = fmaxf(m, __shfl_xor(m, off));
        if ((tid & 63) == 0) wred[tid >> 6] = m;
    }
    __syncthreads();
    float M = fmaxf(wred[0], wred[1]);
    if (tid < NCHUNK) {
        float z = lbuf[b * NCHUNK + tid] * __expf(mbuf[b * NCHUNK + tid] - M);
#pragma unroll
        for (int off = 32; off >= 1; off >>= 1) z += __shfl_xor(z, off);
        if ((tid & 63) == 0) wred[2 + (tid >> 6)] = z;
    }
    __syncthreads();
    float invZ = 1.f / (wred[2] + wred[3]);

    if (part_id < 8) {
        size_t off = (size_t)b * S_ + part_id * 1024;
        floatx4 v = *reinterpret_cast<const floatx4*>(scores + off + tid * 4);
        floatx4 w;
#pragma unroll
        for (int j = 0; j < 4; ++j) w[j] = __expf(v[j] - M) * invZ;
        *reinterpret_cast<floatx4*>(out + B_ * D_ + off + tid * 4) = w;
    } else {
        if (tid < NCHUNK) alpha[tid] = __expf(mbuf[b * NCHUNK + tid] - M) * invZ;
        __syncthreads();
        float acc = 0.f;
#pragma unroll 8
        for (int c = 0; c < NCHUNK; ++c)
            acc = fmaf(alpha[c], cpart[((size_t)b * NCHUNK + c) * D_ + tid], acc);
        out[b * D_ + tid] = acc;
    }
}

extern "C" void kernel_launch(void* const* d_in, const int* in_sizes, int n_in,
                              void* d_out, int out_size, void* d_ws, size_t ws_size,
                              hipStream_t stream) {
    const float* query  = (const float*)d_in[0];
    const float* values = (const float*)d_in[1];
    const float* W1     = (const float*)d_in[2];
    const float* W2     = (const float*)d_in[3];
    const float* V      = (const float*)d_in[4];
    float* out = (float*)d_out;

    char* ws = (char*)d_ws;
    unsigned short* w1t = (unsigned short*)ws;               ws += 65536;           // 64 KiB
    float* pq     = (float*)ws;                              ws += 16384;           // 16 KiB
    float* scores = (float*)ws;                              ws += B_ * S_ * 4;     // 1 MiB
    float* mbuf   = (float*)ws;                              ws += B_ * NCHUNK * 4; // 16 KiB
    float* lbuf   = (float*)ws;                              ws += B_ * NCHUNK * 4; // 16 KiB
    float* cpart  = (float*)ws;                                                    // 4 MiB

    prep_kernel<<<dim3(32), dim3(128), 0, stream>>>(query, W1, W2, pq, w1t);
    fused_kernel<<<dim3(NCHUNK, B_), dim3(256), 0, stream>>>(values, w1t, pq, V,
                                                             scores, mbuf, lbuf, cpart);
    finalize_kernel<<<dim3(B_, 9), dim3(256), 0, stream>>>(scores, mbuf, lbuf, cpart, out);
}

// Round 4
// 383.964 us; speedup vs baseline: 3.1606x; 1.0087x over previous
//
#include <hip/hip_runtime.h>
#include <stdint.h>

#define B_ 32
#define S_ 8192
#define D_ 256
#define Q_ 256
#define U_ 128
#define NCHUNK 128   // S_/64 chunks per batch (M=64 rows per block)

typedef float floatx4 __attribute__((ext_vector_type(4)));
typedef float f32x4 __attribute__((ext_vector_type(4)));
typedef __bf16 bf16x8 __attribute__((ext_vector_type(8)));
typedef unsigned short ushortx4 __attribute__((ext_vector_type(4)));
typedef unsigned short ushortx8 __attribute__((ext_vector_type(8)));

static __device__ __forceinline__ unsigned short f2bf(float f) {
    unsigned int x = __builtin_bit_cast(unsigned int, f);
    x += 0x7FFFu + ((x >> 16) & 1u);   // RNE (inputs are finite/normal)
    return (unsigned short)(x >> 16);
}

static __device__ __forceinline__ float bf2f(unsigned short u) {
    unsigned int x = ((unsigned int)u) << 16;
    return __builtin_bit_cast(float, x);
}

static __device__ __forceinline__ float fast_tanh(float x) {
    x = fminf(15.f, fmaxf(-15.f, x));
    float e = __expf(2.f * x);
    return __fdividef(e - 1.f, e + 1.f);
}

// Kernel 1: 256 threads/block. Lanes 0-127: proj_q[b][u] (256-FMA chain,
// 4-way ILP). Lanes 128-255 concurrently: W1^T -> bf16 fragment-major,
// element (n,k) at (k>>5)*4096 + n*32 + (k&31). (R3 did both jobs serially
// in the same 128 threads.)
__global__ __launch_bounds__(256) void prep_kernel(
        const float* __restrict__ query, const float* __restrict__ W1,
        const float* __restrict__ W2, float* __restrict__ pq,
        unsigned short* __restrict__ w1t) {
    int b = blockIdx.x;
    int t = threadIdx.x;  // 0..255
    __shared__ float qrow[Q_];
    qrow[t] = query[b * Q_ + t];
    __syncthreads();
    if (t < 128) {
        float a0 = 0.f, a1 = 0.f, a2 = 0.f, a3 = 0.f;   // 4-way ILP on the chain
#pragma unroll 4
        for (int q = 0; q < Q_; q += 4) {
            a0 = fmaf(qrow[q],     W2[q * U_ + t],       a0);
            a1 = fmaf(qrow[q + 1], W2[(q + 1) * U_ + t], a1);
            a2 = fmaf(qrow[q + 2], W2[(q + 2) * U_ + t], a2);
            a3 = fmaf(qrow[q + 3], W2[(q + 3) * U_ + t], a3);
        }
        pq[b * U_ + t] = (a0 + a1) + (a2 + a3);
    } else {
        int tt = t - 128;
        int base = (b * 128 + tt) * 8;    // 8 consecutive k, same n
        int n = base >> 8, k0 = base & 255;
        ushortx8 u;
#pragma unroll
        for (int j = 0; j < 8; ++j) u[j] = f2bf(W1[(k0 + j) * U_ + n]);
        *reinterpret_cast<ushortx8*>(&w1t[(k0 >> 5) * 4096 + n * 32 + (k0 & 31)]) = u;
    }
}

// Kernel 2 (fused): per (b, 64-row chunk):
//   A tile 64x256 bf16 in LDS (32 KiB, XOR swizzle). Staging is FULLY
//   SEQUENTIAL over the block's 64 KiB of values, with a 4-pass register
//   lookahead (8 outstanding dwordx4/thread) so the HBM stream stays deep.
//   Each wave writes a contiguous 1 KiB swizzled LDS span -> conflict-free.
//   Single barrier, then the 8-ksg MFMA sweep (B fragments direct from
//   L2-hot w1t, register double-buffer). 4 blocks/CU give inter-block TLP.
//   Scores -> ws; local softmax stats; partial context from the LDS bf16
//   tile (single HBM pass over values). NO device-scope fences (R2 lesson:
//   per-block __threadfence => buffer_wbl2/inv per block => 15x regression).
__global__ __launch_bounds__(256, 4) void fused_kernel(
        const float* __restrict__ values, const unsigned short* __restrict__ w1t,
        const float* __restrict__ pq, const float* __restrict__ V,
        float* __restrict__ scores, float* __restrict__ mbuf,
        float* __restrict__ lbuf, float* __restrict__ cpart) {
    __shared__ __align__(16) char smem[32768 + 4096 + 512 + 256];
    unsigned short* As = (unsigned short*)smem;            // 64 x 256 ushorts, swizzled
    floatx4* cbuf = (floatx4*)(smem + 32768);              // 256 f4
    float* part = (float*)(smem + 32768 + 4096);           // 128 f
    float* parr = (float*)(smem + 32768 + 4096 + 512);     // 64 f

    int b = blockIdx.y;
    int cid = blockIdx.x;
    int s0 = cid * 64;
    int tid = threadIdx.x;
    int lane = tid & 63;
    int wave = tid >> 6;
    int wr = wave >> 1, wc = wave & 1;
    int cc = lane & 15, qg = lane >> 4;
    int cc7 = cc & 7;

    const float* vb = values + ((size_t)b * S_ + s0) * D_;

    f32x4 acc[2][4];
#pragma unroll
    for (int mt = 0; mt < 2; ++mt)
#pragma unroll
        for (int nt = 0; nt < 4; ++nt) acc[mt][nt] = (f32x4){0.f, 0.f, 0.f, 0.f};

    // A staging: sequential 64 KiB burst. Pass p covers rows [p*8, p*8+8):
    // thread t handles row p*8 + (t>>5), 16-B chunk (t&31) -> one
    // ds_write_b128; a wave writes 2 full rows = contiguous 1 KiB of LDS
    // (XOR swizzle is a within-row permutation) -> conflict-free.
    int srow = tid >> 5;        // 0..7
    int sc = tid & 31;          // 16-B chunk index within row
    floatx4 areg[4][2];         // 4-pass lookahead
    auto load_p = [&](int p) {
        const float* src = vb + (size_t)(p * 8 + srow) * D_ + sc * 8;
        areg[p & 3][0] = *reinterpret_cast<const floatx4*>(src);
        areg[p & 3][1] = *reinterpret_cast<const floatx4*>(src + 4);
    };
    auto write_p = [&](int p) {
        int row = p * 8 + srow;
        ushortx8 u;
#pragma unroll
        for (int e = 0; e < 4; ++e) {
            u[e]     = f2bf(areg[p & 3][0][e]);
            u[e + 4] = f2bf(areg[p & 3][1][e]);
        }
        *reinterpret_cast<ushortx8*>(&As[row * 256 + ((sc ^ (row & 7)) << 3)]) = u;
    };

    // B fragment register double-buffer, direct from global (L2/L1-hot).
    bf16x8 bb[2][4];
    const unsigned short* wbase = w1t + (wc * 64 + cc) * 32 + qg * 8;
    auto load_b = [&](int ksg, int buf) {
#pragma unroll
        for (int nt = 0; nt < 4; ++nt)
            bb[buf][nt] = *reinterpret_cast<const bf16x8*>(wbase + ksg * 4096 + nt * 512);
    };

    // A-loads lead (HBM-critical stream), then the B prologue load.
    load_p(0); load_p(1); load_p(2); load_p(3);
    load_b(0, 0);
#pragma unroll
    for (int p = 0; p < 8; ++p) {
        write_p(p);
        if (p < 4) load_p(p + 4);
    }
    __syncthreads();

    // MFMA sweep: 8 ksg, no intermediate barriers.
#pragma unroll
    for (int ksg = 0; ksg < 8; ++ksg) {
        if (ksg < 7) load_b(ksg + 1, (ksg + 1) & 1);
        bf16x8 af[2];
#pragma unroll
        for (int mt = 0; mt < 2; ++mt) {
            int r = wr * 32 + mt * 16 + cc;
            af[mt] = *reinterpret_cast<const bf16x8*>(
                &As[r * 256 + (((ksg * 4 + qg) ^ cc7) << 3)]);
        }
        __builtin_amdgcn_s_setprio(1);
#pragma unroll
        for (int mt = 0; mt < 2; ++mt)
#pragma unroll
            for (int nt = 0; nt < 4; ++nt)
                acc[mt][nt] = __builtin_amdgcn_mfma_f32_16x16x32_bf16(
                    af[mt], bb[ksg & 1][nt], acc[mt][nt], 0, 0, 0);
        __builtin_amdgcn_s_setprio(0);
    }

    // tanh + dot-V epilogue -> per-row score partials
    float Vu[4], pqu[4];
#pragma unroll
    for (int nt = 0; nt < 4; ++nt) {
        int u = wc * 64 + nt * 16 + cc;
        Vu[nt] = V[u];
        pqu[nt] = pq[b * U_ + u];
    }
#pragma unroll
    for (int mt = 0; mt < 2; ++mt) {
#pragma unroll
        for (int r = 0; r < 4; ++r) {
            float s = 0.f;
#pragma unroll
            for (int nt = 0; nt < 4; ++nt)
                s += Vu[nt] * fast_tanh(acc[mt][nt][r] + pqu[nt]);
            s += __shfl_xor(s, 1);
            s += __shfl_xor(s, 2);
            s += __shfl_xor(s, 4);
            s += __shfl_xor(s, 8);
            if (cc == 0) part[wc * 64 + wr * 32 + mt * 16 + qg * 4 + r] = s;
        }
    }
    __syncthreads();
    // combine halves, write scores, butterfly max+sum (result in every lane)
    if (tid < 64) {
        float sc2 = part[tid] + part[64 + tid];
        scores[(size_t)b * S_ + s0 + tid] = sc2;
        float m = sc2;
#pragma unroll
        for (int off = 32; off >= 1; off >>= 1) m = fmaxf(m, __shfl_xor(m, off));
        float p = __expf(sc2 - m);
        float l = p;
#pragma unroll
        for (int off = 32; off >= 1; off >>= 1) l += __shfl_xor(l, off);
        parr[tid] = p;
        if (tid == 0) { mbuf[b * NCHUNK + cid] = m; lbuf[b * NCHUNK + cid] = l; }
    }
    __syncthreads();

    // partial context from LDS bf16 tile (wave-uniform row; conflict-free).
    int g = tid & 63, sub = tid >> 6;
    floatx4 acc4 = {0.f, 0.f, 0.f, 0.f};
#pragma unroll 4
    for (int i = 0; i < 16; ++i) {
        int r = i * 4 + sub;
        float w = parr[r];
        int addr = r * 256 + (((g >> 1) ^ (r & 7)) << 3) + (g & 1) * 4;
        ushortx4 u = *reinterpret_cast<const ushortx4*>(&As[addr]);
        acc4[0] = fmaf(bf2f(u[0]), w, acc4[0]);
        acc4[1] = fmaf(bf2f(u[1]), w, acc4[1]);
        acc4[2] = fmaf(bf2f(u[2]), w, acc4[2]);
        acc4[3] = fmaf(bf2f(u[3]), w, acc4[3]);
    }
    cbuf[tid] = acc4;
    __syncthreads();
    if (tid < 64) {
        floatx4 r4 = cbuf[tid] + cbuf[tid + 64] + cbuf[tid + 128] + cbuf[tid + 192];
        *reinterpret_cast<floatx4*>(cpart + ((size_t)b * NCHUNK + cid) * D_ + g * 4) = r4;
    }
}

// Kernel 3: grid (B_, 9). y<8: write 1024 weights; y==8: combined context.
__global__ __launch_bounds__(256) void finalize_kernel(
        const float* __restrict__ scores, const float* __restrict__ mbuf,
        const float* __restrict__ lbuf, const float* __restrict__ cpart,
        float* __restrict__ out) {
    int b = blockIdx.x;
    int part_id = blockIdx.y;
    int tid = threadIdx.x;
    __shared__ float wred[4];
    __shared__ float alpha[NCHUNK];
    if (tid < NCHUNK) {
        float m = mbuf[b * NCHUNK + tid];
#pragma unroll
        for (int off = 32; off >= 1; off >>= 1) m = fmaxf(m, __shfl_xor(m, off));
        if ((tid & 63) == 0) wred[tid >> 6] = m;
    }
    __syncthreads();
    float M = fmaxf(wred[0], wred[1]);
    if (tid < NCHUNK) {
        float z = lbuf[b * NCHUNK + tid] * __expf(mbuf[b * NCHUNK + tid] - M);
#pragma unroll
        for (int off = 32; off >= 1; off >>= 1) z += __shfl_xor(z, off);
        if ((tid & 63) == 0) wred[2 + (tid >> 6)] = z;
    }
    __syncthreads();
    float invZ = 1.f / (wred[2] + wred[3]);

    if (part_id < 8) {
        size_t off = (size_t)b * S_ + part_id * 1024;
        floatx4 v = *reinterpret_cast<const floatx4*>(scores + off + tid * 4);
        floatx4 w;
#pragma unroll
        for (int j = 0; j < 4; ++j) w[j] = __expf(v[j] - M) * invZ;
        *reinterpret_cast<floatx4*>(out + B_ * D_ + off + tid * 4) = w;
    } else {
        if (tid < NCHUNK) alpha[tid] = __expf(mbuf[b * NCHUNK + tid] - M) * invZ;
        __syncthreads();
        float acc = 0.f;
#pragma unroll 8
        for (int c = 0; c < NCHUNK; ++c)
            acc = fmaf(alpha[c], cpart[((size_t)b * NCHUNK + c) * D_ + tid], acc);
        out[b * D_ + tid] = acc;
    }
}

extern "C" void kernel_launch(void* const* d_in, const int* in_sizes, int n_in,
                              void* d_out, int out_size, void* d_ws, size_t ws_size,
                              hipStream_t stream) {
    const float* query  = (const float*)d_in[0];
    const float* values = (const float*)d_in[1];
    const float* W1     = (const float*)d_in[2];
    const float* W2     = (const float*)d_in[3];
    const float* V      = (const float*)d_in[4];
    float* out = (float*)d_out;

    char* ws = (char*)d_ws;
    unsigned short* w1t = (unsigned short*)ws;               ws += 65536;           // 64 KiB
    float* pq     = (float*)ws;                              ws += 16384;           // 16 KiB
    float* scores = (float*)ws;                              ws += B_ * S_ * 4;     // 1 MiB
    float* mbuf   = (float*)ws;                              ws += B_ * NCHUNK * 4; // 16 KiB
    float* lbuf   = (float*)ws;                              ws += B_ * NCHUNK * 4; // 16 KiB
    float* cpart  = (float*)ws;                                                    // 4 MiB

    prep_kernel<<<dim3(32), dim3(256), 0, stream>>>(query, W1, W2, pq, w1t);
    fused_kernel<<<dim3(NCHUNK, B_), dim3(256), 0, stream>>>(values, w1t, pq, V,
                                                             scores, mbuf, lbuf, cpart);
    finalize_kernel<<<dim3(B_, 9), dim3(256), 0, stream>>>(scores, mbuf, lbuf, cpart, out);
}

// Round 5
// 382.740 us; speedup vs baseline: 3.1707x; 1.0032x over previous
//
#include <hip/hip_runtime.h>
#include <stdint.h>

#define B_ 32
#define S_ 8192
#define D_ 256
#define Q_ 256
#define U_ 128
#define NCHUNK 128   // S_/64 chunks per batch (M=64 rows per block)

typedef float floatx4 __attribute__((ext_vector_type(4)));
typedef float f32x4 __attribute__((ext_vector_type(4)));
typedef __bf16 bf16x8 __attribute__((ext_vector_type(8)));
typedef unsigned short ushortx4 __attribute__((ext_vector_type(4)));
typedef unsigned short ushortx8 __attribute__((ext_vector_type(8)));

static __device__ __forceinline__ unsigned short f2bf(float f) {
    unsigned int x = __builtin_bit_cast(unsigned int, f);
    x += 0x7FFFu + ((x >> 16) & 1u);   // RNE (inputs are finite/normal)
    return (unsigned short)(x >> 16);
}

static __device__ __forceinline__ float bf2f(unsigned short u) {
    unsigned int x = ((unsigned int)u) << 16;
    return __builtin_bit_cast(float, x);
}

static __device__ __forceinline__ float fast_tanh(float x) {
    x = fminf(15.f, fmaxf(-15.f, x));
    float e = __expf(2.f * x);
    return __fdividef(e - 1.f, e + 1.f);
}

// Kernel 1, grid (32, 2):
//  y==0 (per b): pq[b][u] = sum_q query[b][q]*W2[q][u] with a 2-way k-split
//   across 256 threads (chain length 128, 4-way ILP) + LDS combine.
//  y==1 (b = k-slice): W1^T -> bf16 fragment-major, element (n,k) at
//   (k>>5)*4096 + n*32 + (k&31). Each block does 1/32 of the transpose
//   (8 k-rows), coalesced 512B row loads, aligned ushortx4 stores.
//   (R4 did the whole transpose redundantly in all 32 blocks with
//   stride-512B uncoalesced loads -> ~16x overfetch.)
__global__ __launch_bounds__(256) void prep_kernel(
        const float* __restrict__ query, const float* __restrict__ W1,
        const float* __restrict__ W2, float* __restrict__ pq,
        unsigned short* __restrict__ w1t) {
    int b = blockIdx.x;
    int t = threadIdx.x;  // 0..255
    if (blockIdx.y == 0) {
        __shared__ float qrow[Q_];
        __shared__ float halfs[2][U_];
        qrow[t] = query[b * Q_ + t];
        __syncthreads();
        int u = t & 127, kh = t >> 7;
        const float* qh = qrow + kh * 128;
        const float* w2p = W2 + (size_t)(kh * 128) * U_ + u;
        float a0 = 0.f, a1 = 0.f, a2 = 0.f, a3 = 0.f;   // 4-way ILP
#pragma unroll 4
        for (int q = 0; q < 128; q += 4) {
            a0 = fmaf(qh[q],     w2p[(size_t)q * U_],       a0);
            a1 = fmaf(qh[q + 1], w2p[(size_t)(q + 1) * U_], a1);
            a2 = fmaf(qh[q + 2], w2p[(size_t)(q + 2) * U_], a2);
            a3 = fmaf(qh[q + 3], w2p[(size_t)(q + 3) * U_], a3);
        }
        halfs[kh][u] = (a0 + a1) + (a2 + a3);
        __syncthreads();
        if (t < 128) pq[b * U_ + t] = halfs[0][t] + halfs[1][t];
    } else {
        // k-slice [b*8, b*8+8): thread handles n = t&127, k = k0..k0+3.
        int n = t & 127;
        int k0 = b * 8 + (t >> 7) * 4;
        ushortx4 u4;
#pragma unroll
        for (int j = 0; j < 4; ++j) u4[j] = f2bf(W1[(size_t)(k0 + j) * U_ + n]);
        *reinterpret_cast<ushortx4*>(&w1t[(k0 >> 5) * 4096 + n * 32 + (k0 & 31)]) = u4;
    }
}

// Kernel 2 (fused): per (b, 64-row chunk):
//   A tile 64x256 bf16 in LDS (32 KiB, XOR swizzle). Staging is FULLY
//   SEQUENTIAL over the block's 64 KiB of values, with a 4-pass register
//   lookahead (8 outstanding dwordx4/thread) so the HBM stream stays deep.
//   Each wave writes a contiguous 1 KiB swizzled LDS span -> conflict-free.
//   Single barrier, then the 8-ksg MFMA sweep (B fragments direct from
//   L2-hot w1t, register double-buffer). 4 blocks/CU give inter-block TLP.
//   Scores -> ws; local softmax stats; partial context from the LDS bf16
//   tile (single HBM pass over values). NO device-scope fences (R2 lesson:
//   per-block __threadfence => buffer_wbl2/inv per block => 15x regression).
__global__ __launch_bounds__(256, 4) void fused_kernel(
        const float* __restrict__ values, const unsigned short* __restrict__ w1t,
        const float* __restrict__ pq, const float* __restrict__ V,
        float* __restrict__ scores, float* __restrict__ mbuf,
        float* __restrict__ lbuf, float* __restrict__ cpart) {
    __shared__ __align__(16) char smem[32768 + 4096 + 512 + 256];
    unsigned short* As = (unsigned short*)smem;            // 64 x 256 ushorts, swizzled
    floatx4* cbuf = (floatx4*)(smem + 32768);              // 256 f4
    float* part = (float*)(smem + 32768 + 4096);           // 128 f
    float* parr = (float*)(smem + 32768 + 4096 + 512);     // 64 f

    int b = blockIdx.y;
    int cid = blockIdx.x;
    int s0 = cid * 64;
    int tid = threadIdx.x;
    int lane = tid & 63;
    int wave = tid >> 6;
    int wr = wave >> 1, wc = wave & 1;
    int cc = lane & 15, qg = lane >> 4;
    int cc7 = cc & 7;

    const float* vb = values + ((size_t)b * S_ + s0) * D_;

    f32x4 acc[2][4];
#pragma unroll
    for (int mt = 0; mt < 2; ++mt)
#pragma unroll
        for (int nt = 0; nt < 4; ++nt) acc[mt][nt] = (f32x4){0.f, 0.f, 0.f, 0.f};

    // A staging: sequential 64 KiB burst. Pass p covers rows [p*8, p*8+8):
    // thread t handles row p*8 + (t>>5), 16-B chunk (t&31) -> one
    // ds_write_b128; a wave writes 2 full rows = contiguous 1 KiB of LDS
    // (XOR swizzle is a within-row permutation) -> conflict-free.
    int srow = tid >> 5;        // 0..7
    int sc = tid & 31;          // 16-B chunk index within row
    floatx4 areg[4][2];         // 4-pass lookahead
    auto load_p = [&](int p) {
        const float* src = vb + (size_t)(p * 8 + srow) * D_ + sc * 8;
        areg[p & 3][0] = *reinterpret_cast<const floatx4*>(src);
        areg[p & 3][1] = *reinterpret_cast<const floatx4*>(src + 4);
    };
    auto write_p = [&](int p) {
        int row = p * 8 + srow;
        ushortx8 u;
#pragma unroll
        for (int e = 0; e < 4; ++e) {
            u[e]     = f2bf(areg[p & 3][0][e]);
            u[e + 4] = f2bf(areg[p & 3][1][e]);
        }
        *reinterpret_cast<ushortx8*>(&As[row * 256 + ((sc ^ (row & 7)) << 3)]) = u;
    };

    // B fragment register double-buffer, direct from global (L2/L1-hot).
    bf16x8 bb[2][4];
    const unsigned short* wbase = w1t + (wc * 64 + cc) * 32 + qg * 8;
    auto load_b = [&](int ksg, int buf) {
#pragma unroll
        for (int nt = 0; nt < 4; ++nt)
            bb[buf][nt] = *reinterpret_cast<const bf16x8*>(wbase + ksg * 4096 + nt * 512);
    };

    // A-loads lead (HBM-critical stream), then the B prologue load.
    load_p(0); load_p(1); load_p(2); load_p(3);
    load_b(0, 0);
#pragma unroll
    for (int p = 0; p < 8; ++p) {
        write_p(p);
        if (p < 4) load_p(p + 4);
    }
    __syncthreads();

    // MFMA sweep: 8 ksg, no intermediate barriers.
#pragma unroll
    for (int ksg = 0; ksg < 8; ++ksg) {
        if (ksg < 7) load_b(ksg + 1, (ksg + 1) & 1);
        bf16x8 af[2];
#pragma unroll
        for (int mt = 0; mt < 2; ++mt) {
            int r = wr * 32 + mt * 16 + cc;
            af[mt] = *reinterpret_cast<const bf16x8*>(
                &As[r * 256 + (((ksg * 4 + qg) ^ cc7) << 3)]);
        }
        __builtin_amdgcn_s_setprio(1);
#pragma unroll
        for (int mt = 0; mt < 2; ++mt)
#pragma unroll
            for (int nt = 0; nt < 4; ++nt)
                acc[mt][nt] = __builtin_amdgcn_mfma_f32_16x16x32_bf16(
                    af[mt], bb[ksg & 1][nt], acc[mt][nt], 0, 0, 0);
        __builtin_amdgcn_s_setprio(0);
    }

    // tanh + dot-V epilogue -> per-row score partials
    float Vu[4], pqu[4];
#pragma unroll
    for (int nt = 0; nt < 4; ++nt) {
        int u = wc * 64 + nt * 16 + cc;
        Vu[nt] = V[u];
        pqu[nt] = pq[b * U_ + u];
    }
#pragma unroll
    for (int mt = 0; mt < 2; ++mt) {
#pragma unroll
        for (int r = 0; r < 4; ++r) {
            float s = 0.f;
#pragma unroll
            for (int nt = 0; nt < 4; ++nt)
                s += Vu[nt] * fast_tanh(acc[mt][nt][r] + pqu[nt]);
            s += __shfl_xor(s, 1);
            s += __shfl_xor(s, 2);
            s += __shfl_xor(s, 4);
            s += __shfl_xor(s, 8);
            if (cc == 0) part[wc * 64 + wr * 32 + mt * 16 + qg * 4 + r] = s;
        }
    }
    __syncthreads();
    // combine halves, write scores, butterfly max+sum (result in every lane)
    if (tid < 64) {
        float sc2 = part[tid] + part[64 + tid];
        scores[(size_t)b * S_ + s0 + tid] = sc2;
        float m = sc2;
#pragma unroll
        for (int off = 32; off >= 1; off >>= 1) m = fmaxf(m, __shfl_xor(m, off));
        float p = __expf(sc2 - m);
        float l = p;
#pragma unroll
        for (int off = 32; off >= 1; off >>= 1) l += __shfl_xor(l, off);
        parr[tid] = p;
        if (tid == 0) { mbuf[b * NCHUNK + cid] = m; lbuf[b * NCHUNK + cid] = l; }
    }
    __syncthreads();

    // partial context from LDS bf16 tile (wave-uniform row; conflict-free).
    int g = tid & 63, sub = tid >> 6;
    floatx4 acc4 = {0.f, 0.f, 0.f, 0.f};
#pragma unroll 4
    for (int i = 0; i < 16; ++i) {
        int r = i * 4 + sub;
        float w = parr[r];
        int addr = r * 256 + (((g >> 1) ^ (r & 7)) << 3) + (g & 1) * 4;
        ushortx4 u = *reinterpret_cast<const ushortx4*>(&As[addr]);
        acc4[0] = fmaf(bf2f(u[0]), w, acc4[0]);
        acc4[1] = fmaf(bf2f(u[1]), w, acc4[1]);
        acc4[2] = fmaf(bf2f(u[2]), w, acc4[2]);
        acc4[3] = fmaf(bf2f(u[3]), w, acc4[3]);
    }
    cbuf[tid] = acc4;
    __syncthreads();
    if (tid < 64) {
        floatx4 r4 = cbuf[tid] + cbuf[tid + 64] + cbuf[tid + 128] + cbuf[tid + 192];
        *reinterpret_cast<floatx4*>(cpart + ((size_t)b * NCHUNK + cid) * D_ + g * 4) = r4;
    }
}

// Kernel 3: grid (B_, 9). y<8: write 1024 weights; y==8: combined context.
__global__ __launch_bounds__(256) void finalize_kernel(
        const float* __restrict__ scores, const float* __restrict__ mbuf,
        const float* __restrict__ lbuf, const float* __restrict__ cpart,
        float* __restrict__ out) {
    int b = blockIdx.x;
    int part_id = blockIdx.y;
    int tid = threadIdx.x;
    __shared__ float wred[4];
    __shared__ float alpha[NCHUNK];
    if (tid < NCHUNK) {
        float m = mbuf[b * NCHUNK + tid];
#pragma unroll
        for (int off = 32; off >= 1; off >>= 1) m = fmaxf(m, __shfl_xor(m, off));
        if ((tid & 63) == 0) wred[tid >> 6] = m;
    }
    __syncthreads();
    float M = fmaxf(wred[0], wred[1]);
    if (tid < NCHUNK) {
        float z = lbuf[b * NCHUNK + tid] * __expf(mbuf[b * NCHUNK + tid] - M);
#pragma unroll
        for (int off = 32; off >= 1; off >>= 1) z += __shfl_xor(z, off);
        if ((tid & 63) == 0) wred[2 + (tid >> 6)] = z;
    }
    __syncthreads();
    float invZ = 1.f / (wred[2] + wred[3]);

    if (part_id < 8) {
        size_t off = (size_t)b * S_ + part_id * 1024;
        floatx4 v = *reinterpret_cast<const floatx4*>(scores + off + tid * 4);
        floatx4 w;
#pragma unroll
        for (int j = 0; j < 4; ++j) w[j] = __expf(v[j] - M) * invZ;
        *reinterpret_cast<floatx4*>(out + B_ * D_ + off + tid * 4) = w;
    } else {
        if (tid < NCHUNK) alpha[tid] = __expf(mbuf[b * NCHUNK + tid] - M) * invZ;
        __syncthreads();
        float acc = 0.f;
#pragma unroll 8
        for (int c = 0; c < NCHUNK; ++c)
            acc = fmaf(alpha[c], cpart[((size_t)b * NCHUNK + c) * D_ + tid], acc);
        out[b * D_ + tid] = acc;
    }
}

extern "C" void kernel_launch(void* const* d_in, const int* in_sizes, int n_in,
                              void* d_out, int out_size, void* d_ws, size_t ws_size,
                              hipStream_t stream) {
    const float* query  = (const float*)d_in[0];
    const float* values = (const float*)d_in[1];
    const float* W1     = (const float*)d_in[2];
    const float* W2     = (const float*)d_in[3];
    const float* V      = (const float*)d_in[4];
    float* out = (float*)d_out;

    char* ws = (char*)d_ws;
    unsigned short* w1t = (unsigned short*)ws;               ws += 65536;           // 64 KiB
    float* pq     = (float*)ws;                              ws += 16384;           // 16 KiB
    float* scores = (float*)ws;                              ws += B_ * S_ * 4;     // 1 MiB
    float* mbuf   = (float*)ws;                              ws += B_ * NCHUNK * 4; // 16 KiB
    float* lbuf   = (float*)ws;                              ws += B_ * NCHUNK * 4; // 16 KiB
    float* cpart  = (float*)ws;                                                    // 4 MiB

    prep_kernel<<<dim3(32, 2), dim3(256), 0, stream>>>(query, W1, W2, pq, w1t);
    fused_kernel<<<dim3(NCHUNK, B_), dim3(256), 0, stream>>>(values, w1t, pq, V,
                                                             scores, mbuf, lbuf, cpart);
    finalize_kernel<<<dim3(B_, 9), dim3(256), 0, stream>>>(scores, mbuf, lbuf, cpart, out);
}